// Round 8
// baseline (94.933 us; speedup 1.0000x reference)
//
#include <hip/hip_runtime.h>
#include <hip/hip_bf16.h>

// EDMultiheadRetention: S=128, D=4096, H=32, hd=128
// Pipeline: prep (cast x + kvsT) -> gemm_split (KS=4; BK=64; A via global_load_lds
//           3-buf 2-ahead; W global->reg->MFMA direct, 2-iter convert lead) -> reduce -> heads

typedef __bf16 bf16x8 __attribute__((ext_vector_type(8)));
typedef float f32x4 __attribute__((ext_vector_type(4)));

typedef __attribute__((address_space(1))) const unsigned g_u32;
typedef __attribute__((address_space(3))) unsigned l_u32;

static __device__ __forceinline__ f32x4 mfma_bf16(bf16x8 a, bf16x8 b, f32x4 c) {
  return __builtin_amdgcn_mfma_f32_16x16x32_bf16(a, b, c, 0, 0, 0);
}

static __device__ __forceinline__ bf16x8 cvt8(float4 lo, float4 hi) {
  return (bf16x8){(__bf16)lo.x, (__bf16)lo.y, (__bf16)lo.z, (__bf16)lo.w,
                  (__bf16)hi.x, (__bf16)hi.y, (__bf16)hi.z, (__bf16)hi.w};
}

#define WAIT_VM20() asm volatile("s_waitcnt vmcnt(20)" ::: "memory")
#define WAIT_VM8() asm volatile("s_waitcnt vmcnt(8)" ::: "memory")
#define WAIT_VM0() asm volatile("s_waitcnt vmcnt(0)" ::: "memory")
#define SCHED_FENCE() __builtin_amdgcn_sched_barrier(0)

// ---------------- kernel 1: cast x -> bf16 (blocks 0..255), kvsT prep (256..383)
__global__ __launch_bounds__(256) void prep_kernel(const float* __restrict__ x,
                                                   __bf16* __restrict__ xb,
                                                   const float* __restrict__ kvs,
                                                   const float* __restrict__ alpha,
                                                   __bf16* __restrict__ kvsT) {
  __shared__ float lds[32][129];
  const int tid = threadIdx.x;
  if (blockIdx.x < 256) {
    const int i = (blockIdx.x * 256 + tid) * 8;
    float4 a = *(const float4*)(x + i);
    float4 b = *(const float4*)(x + i + 4);
    *(bf16x8*)(xb + i) = cvt8(a, b);
    return;
  }
  const int bid = blockIdx.x - 256;
  const int h = bid >> 2, dq = bid & 3;
  const int j = tid & 127, dg = tid >> 7;
  const int d0 = dq * 32;
#pragma unroll
  for (int i = 0; i < 16; ++i) {
    const int dloc = dg * 16 + i;
    const int d = d0 + dloc;
    const float dS = exp2f(128.f * log2f(alpha[h * 128 + d]));
    lds[dloc][j] = kvs[(size_t)h * 16384 + d * 128 + j] * dS;
  }
  __syncthreads();
  const int jj = tid >> 1, dh = tid & 1;
  bf16x8 a0, a1;
#pragma unroll
  for (int i = 0; i < 8; ++i) a0[i] = (__bf16)lds[dh * 16 + i][jj];
#pragma unroll
  for (int i = 0; i < 8; ++i) a1[i] = (__bf16)lds[dh * 16 + 8 + i][jj];
  *(bf16x8*)(kvsT + (size_t)h * 16384 + jj * 128 + d0 + dh * 16) = a0;
  *(bf16x8*)(kvsT + (size_t)h * 16384 + jj * 128 + d0 + dh * 16 + 8) = a1;
}

// ---------------- kernel 2: split-K GEMM: P[ks][s][n] = x @ W^T (partial) ---
// 256 thr (4 waves 2x2), tile M=128 x N=64, BK=64.
// A: global_load_lds into XOR-swizzled LDS, 3 buffers, DMA issued 2 iters ahead.
// W/B: loaded global->registers (32B contiguous per lane = full 64B lines),
//      2 f32 reg-sets, issue->convert lead = 2 iters, cvt->MFMA directly. No B LDS.
__global__ __launch_bounds__(256, 3) void gemm_split_kernel(const __bf16* __restrict__ xb,
                                                            const float* __restrict__ W,
                                                            float* __restrict__ P,
                                                            int kc_len) {
  __shared__ __bf16 Ald[3][128 * 64];  // 48 KB

  const int tid = threadIdx.x;
  const int wid = tid >> 6, lane = tid & 63;
  const int r0 = lane & 15, l4 = lane >> 4, rr = l4 << 2;
  const int nt = blockIdx.x % 192, ks = blockIdx.x / 192;
  const int n0 = nt * 64;
  const int kb0 = ks * kc_len;
  const int wm = wid & 1, wn = wid >> 1;

  // A staging: 4 DMA units/thread; unit u -> (row=u>>3, phys chunk p=u&7),
  // source logical chunk g = p ^ (row&7); LDS dest linear.
  int a_row[4], a_koff[4];
#pragma unroll
  for (int i = 0; i < 4; ++i) {
    const int u = i * 256 + tid;
    a_row[i] = u >> 3;
    a_koff[i] = ((u & 7) ^ (a_row[i] & 7)) << 3;
  }
  // A fragment read offsets (elements): logical chunk c = kh*4+l4, phys = c^(row&7)
  int a_off[4][2];
#pragma unroll
  for (int mf = 0; mf < 4; ++mf)
#pragma unroll
    for (int kh = 0; kh < 2; ++kh) {
      const int row = wm * 64 + mf * 16 + r0;
      const int p = (kh * 4 + l4) ^ (row & 7);
      a_off[mf][kh] = row * 64 + p * 8;
    }

  // W fragment pointers: frag (nf,kh) -> lane reads W[n0+wn*32+nf*16+r0][kb + (kh*4+l4)*8 ..]
  const float* wfp[2];
#pragma unroll
  for (int nf = 0; nf < 2; ++nf)
    wfp[nf] = W + (size_t)(n0 + wn * 32 + nf * 16 + r0) * 4096 + kb0 + l4 * 8;

  f32x4 acc[4][2];
#pragma unroll
  for (int mf = 0; mf < 4; ++mf)
#pragma unroll
    for (int nf = 0; nf < 2; ++nf) acc[mf][nf] = (f32x4){0.f, 0.f, 0.f, 0.f};

  const int iters = kc_len >> 6;  // 16 at KS=4 (even)

  float4 wAlo[2][2], wAhi[2][2], wBlo[2][2], wBhi[2][2];

#define W_ISSUE(WLO, WHI, KB)                                          \
  _Pragma("unroll") for (int nf = 0; nf < 2; ++nf)                     \
      _Pragma("unroll") for (int kh = 0; kh < 2; ++kh) {               \
    WLO[nf][kh] = *(const float4*)(wfp[nf] + (KB) + kh * 32);          \
    WHI[nf][kh] = *(const float4*)(wfp[nf] + (KB) + kh * 32 + 4);      \
  }

#define A_ISSUE(T_, BUF_)                                                         \
  do {                                                                            \
    const int kb_ = kb0 + (T_) * 64;                                             \
    char* dst_ = (char*)&Ald[0][0] + (BUF_) * 16384;                             \
    _Pragma("unroll") for (int i = 0; i < 4; ++i) {                              \
      const __bf16* src = xb + a_row[i] * 4096 + kb_ + a_koff[i];                \
      __builtin_amdgcn_global_load_lds((g_u32*)(const void*)src,                 \
          (l_u32*)(void*)(dst_ + i * 4096 + wid * 1024), 16, 0, 0);              \
    }                                                                             \
  } while (0)

  // ---- prologue: A(0)->buf0, A(1)->buf1, W(0)->setA, W(1)->setB
  A_ISSUE(0, 0);
  if (iters > 1) A_ISSUE(1, 1);
  W_ISSUE(wAlo, wAhi, 0);
  if (iters > 1) W_ISSUE(wBlo, wBhi, 64);
  if (iters > 1) { WAIT_VM20(); } else { WAIT_VM0(); }  // A(0) landed
  SCHED_FENCE();
  __builtin_amdgcn_s_barrier();
  SCHED_FENCE();

// Iter T: cvt W(T) from SET (issued T-2); issue A(T+2) -> buf (cur+2)%3 and
// W(T+2) -> freed SET; ds_read A-frags from buf cur; 16 MFMA; wait; barrier.
#define GEMM_ITER(T, CUR3, WLO, WHI)                                              \
  do {                                                                            \
    const bool hn1 = (T) + 1 < iters, hn2 = (T) + 2 < iters;                      \
    bf16x8 bfr[2][2];                                                             \
    _Pragma("unroll") for (int nf = 0; nf < 2; ++nf)                              \
        _Pragma("unroll") for (int kh = 0; kh < 2; ++kh)                          \
            bfr[nf][kh] = cvt8(WLO[nf][kh], WHI[nf][kh]);                         \
    if (hn2) {                                                                    \
      const int b2_ = (CUR3) + 2 >= 3 ? (CUR3)-1 : (CUR3) + 2;                    \
      A_ISSUE((T) + 2, b2_);                                                      \
      W_ISSUE(WLO, WHI, ((T) + 2) * 64);                                          \
    }                                                                             \
    SCHED_FENCE(); /* staging issued before compute */                            \
    const __bf16* abase_ = &Ald[0][0] + (CUR3) * 8192;                            \
    bf16x8 af[4][2];                                                              \
    _Pragma("unroll") for (int mf = 0; mf < 4; ++mf)                              \
        _Pragma("unroll") for (int kh = 0; kh < 2; ++kh)                          \
            af[mf][kh] = *(const bf16x8*)(abase_ + a_off[mf][kh]);                \
    _Pragma("unroll") for (int kh = 0; kh < 2; ++kh)                              \
        _Pragma("unroll") for (int mf = 0; mf < 4; ++mf)                          \
            _Pragma("unroll") for (int nf = 0; nf < 2; ++nf)                      \
                acc[mf][nf] = mfma_bf16(af[mf][kh], bfr[nf][kh], acc[mf][nf]);    \
    SCHED_FENCE();                                                                \
    if (hn1) {                                                                    \
      if (hn2) { WAIT_VM20(); } else { WAIT_VM8(); } /* A(T+1) landed */          \
      SCHED_FENCE();                                                              \
      __builtin_amdgcn_s_barrier();                                               \
      SCHED_FENCE();                                                              \
    }                                                                             \
  } while (0)

  {
    int cur = 0;
    for (int t = 0; t < iters; t += 2) {
      GEMM_ITER(t, cur, wAlo, wAhi);
      const int cur1 = cur + 1 >= 3 ? 0 : cur + 1;
      GEMM_ITER(t + 1, cur1, wBlo, wBhi);
      cur = cur1 + 1 >= 3 ? 0 : cur1 + 1;
    }
  }
#undef GEMM_ITER
#undef W_ISSUE
#undef A_ISSUE

  // epilogue: write partials P[ks][s][n]
#pragma unroll
  for (int mf = 0; mf < 4; ++mf)
#pragma unroll
    for (int nf = 0; nf < 2; ++nf)
#pragma unroll
      for (int r = 0; r < 4; ++r) {
        const int s = wm * 64 + mf * 16 + rr + r;
        const int n = n0 + wn * 32 + nf * 16 + r0;
        P[(size_t)ks * 1572864 + (size_t)s * 12288 + n] = acc[mf][nf][r];
      }
}

// ---------------- kernel 3: reduce partials, apply decay, emit bf16 layouts
// qd/kd [h][s][d], kdT/vT [h][d][s]
__global__ __launch_bounds__(256) void reduce_kernel(const float* __restrict__ P,
                                                     const float* __restrict__ alpha,
                                                     __bf16* __restrict__ qd,
                                                     __bf16* __restrict__ kd,
                                                     __bf16* __restrict__ kdT,
                                                     __bf16* __restrict__ vT, int KS) {
  __shared__ float lds[32][129];
  const int bid = blockIdx.x;
  const int which = bid >> 7;  // 0=q 1=k 2=v
  const int rem = bid & 127;
  const int h = rem >> 2, sq = rem & 3;
  const int tid = threadIdx.x;
  const int d = tid & 127, sg = tid >> 7;
  const int n = which * 4096 + h * 128 + d;
  const int s0 = sq * 32;
  const float la = log2f(alpha[h * 128 + d]);

#pragma unroll 4
  for (int si = 0; si < 16; ++si) {
    const int s = s0 + sg * 16 + si;
    float val = 0.f;
#pragma unroll
    for (int ksi = 0; ksi < 4; ++ksi)
      if (ksi < KS) val += P[(size_t)ksi * 1572864 + (size_t)s * 12288 + n];
    if (which == 0)
      val *= exp2f((float)(s - 127) * la - 6.0f);
    else if (which == 1)
      val *= exp2f((float)(127 - s) * la - 6.0f);
    lds[sg * 16 + si][d] = val;
    if (which == 0)
      qd[(size_t)h * 16384 + s * 128 + d] = (__bf16)val;
    else if (which == 1)
      kd[(size_t)h * 16384 + s * 128 + d] = (__bf16)val;
  }
  if (which == 0) return;
  __syncthreads();
  __bf16* outT = (which == 1 ? kdT : vT) + (size_t)h * 16384;
  const int dd = tid >> 1, sh = tid & 1;
  bf16x8 v0, v1;
#pragma unroll
  for (int i = 0; i < 8; ++i) v0[i] = (__bf16)lds[sh * 16 + i][dd];
#pragma unroll
  for (int i = 0; i < 8; ++i) v1[i] = (__bf16)lds[sh * 16 + 8 + i][dd];
  *(bf16x8*)(outT + dd * 128 + s0 + sh * 16) = v0;
  *(bf16x8*)(outT + dd * 128 + s0 + sh * 16 + 8) = v1;
}

// ---------------- kernel 4: per-head retention (all contiguous bf16 loads) --
// bid<128: out rows; bid>=128: new_kvs rows. 128 threads (2 waves).
__global__ __launch_bounds__(128) void heads_kernel(const __bf16* __restrict__ qd,
                                                    const __bf16* __restrict__ kd,
                                                    const __bf16* __restrict__ kdT,
                                                    const __bf16* __restrict__ vT,
                                                    const __bf16* __restrict__ kvsT,
                                                    const float* __restrict__ kvs,
                                                    const float* __restrict__ alpha,
                                                    float* __restrict__ out) {
  const int bid = blockIdx.x;
  const int tid = threadIdx.x;
  const int wid = tid >> 6, lane = tid & 63;
  const int r0 = lane & 15, l4 = lane >> 4;
  const int g8 = l4 << 3, rr = l4 << 2;

  if (bid < 128) {
    const int h = bid >> 2, w = bid & 3;
    const int m_base = w * 32;
    __shared__ __bf16 attn_s[32][136];
    const __bf16* qh = qd + (size_t)h * 16384;
    const __bf16* kh = kd + (size_t)h * 16384;

    f32x4 acc[2][4];
#pragma unroll
    for (int mf = 0; mf < 2; ++mf)
#pragma unroll
      for (int nf = 0; nf < 4; ++nf) acc[mf][nf] = (f32x4){0.f, 0.f, 0.f, 0.f};

    // phase 1: attn cols wid*64..+64
#pragma unroll
    for (int k0 = 0; k0 < 128; k0 += 32) {
      const int kk = k0 + g8;
      bf16x8 a[2];
#pragma unroll
      for (int mf = 0; mf < 2; ++mf)
        a[mf] = *(const bf16x8*)(qh + (m_base + mf * 16 + r0) * 128 + kk);
#pragma unroll
      for (int nf = 0; nf < 4; ++nf) {
        const int jn = wid * 64 + nf * 16 + r0;
        bf16x8 b = *(const bf16x8*)(kh + jn * 128 + kk);
#pragma unroll
        for (int mf = 0; mf < 2; ++mf) acc[mf][nf] = mfma_bf16(a[mf], b, acc[mf][nf]);
      }
    }
#pragma unroll
    for (int mf = 0; mf < 2; ++mf)
#pragma unroll
      for (int nf = 0; nf < 4; ++nf)
#pragma unroll
        for (int r = 0; r < 4; ++r) {
          const int i = m_base + mf * 16 + rr + r;
          const int j = wid * 64 + nf * 16 + r0;
          attn_s[mf * 16 + rr + r][j] = (__bf16)((j <= i) ? acc[mf][nf][r] : 0.f);
        }
    __syncthreads();

    // phase 2: out = gelu(attn @ v + q @ kvsT), d2 in wid*64..+64
#pragma unroll
    for (int mf = 0; mf < 2; ++mf)
#pragma unroll
      for (int nf = 0; nf < 4; ++nf) acc[mf][nf] = (f32x4){0.f, 0.f, 0.f, 0.f};
    const __bf16* vTh = vT + (size_t)h * 16384;
    const __bf16* kvsTh = kvsT + (size_t)h * 16384;
#pragma unroll
    for (int k0 = 0; k0 < 128; k0 += 32) {
      const int kk = k0 + g8;
      bf16x8 a[2];
#pragma unroll
      for (int mf = 0; mf < 2; ++mf)
        a[mf] = *(const bf16x8*)(&attn_s[mf * 16 + r0][kk]);
#pragma unroll
      for (int nf = 0; nf < 4; ++nf) {
        const int d2 = wid * 64 + nf * 16 + r0;
        bf16x8 b = *(const bf16x8*)(vTh + d2 * 128 + kk);
#pragma unroll
        for (int mf = 0; mf < 2; ++mf) acc[mf][nf] = mfma_bf16(a[mf], b, acc[mf][nf]);
      }
    }
#pragma unroll
    for (int k0 = 0; k0 < 128; k0 += 32) {
      const int kk = k0 + g8;
      bf16x8 a[2];
#pragma unroll
      for (int mf = 0; mf < 2; ++mf)
        a[mf] = *(const bf16x8*)(qh + (m_base + mf * 16 + r0) * 128 + kk);
#pragma unroll
      for (int nf = 0; nf < 4; ++nf) {
        const int d2 = wid * 64 + nf * 16 + r0;
        bf16x8 b = *(const bf16x8*)(kvsTh + d2 * 128 + kk);
#pragma unroll
        for (int mf = 0; mf < 2; ++mf) acc[mf][nf] = mfma_bf16(a[mf], b, acc[mf][nf]);
      }
    }
#pragma unroll
    for (int mf = 0; mf < 2; ++mf)
#pragma unroll
      for (int nf = 0; nf < 4; ++nf)
#pragma unroll
        for (int r = 0; r < 4; ++r) {
          const int s = m_base + mf * 16 + rr + r;
          const int d2 = wid * 64 + nf * 16 + r0;
          const float y = acc[mf][nf][r];
          const float u = 0.7978845608028654f * (y + 0.044715f * y * y * y);
          out[(size_t)s * 4096 + h * 128 + d2] = 0.5f * y * (1.f + tanhf(u));
        }
  } else {
    const int b2 = bid - 128;
    const int h = b2 >> 2, w = b2 & 3;
    const int m_base = w * 32;
    const __bf16* kTh = kdT + (size_t)h * 16384;
    const __bf16* vTh = vT + (size_t)h * 16384;

    f32x4 acc[2][4];
#pragma unroll
    for (int mf = 0; mf < 2; ++mf)
#pragma unroll
      for (int nf = 0; nf < 4; ++nf) acc[mf][nf] = (f32x4){0.f, 0.f, 0.f, 0.f};
#pragma unroll
    for (int k0 = 0; k0 < 128; k0 += 32) {
      const int kk = k0 + g8;
      bf16x8 a[2];
#pragma unroll
      for (int mf = 0; mf < 2; ++mf)
        a[mf] = *(const bf16x8*)(kTh + (m_base + mf * 16 + r0) * 128 + kk);
#pragma unroll
      for (int nf = 0; nf < 4; ++nf) {
        const int j = wid * 64 + nf * 16 + r0;
        bf16x8 b = *(const bf16x8*)(vTh + j * 128 + kk);
#pragma unroll
        for (int mf = 0; mf < 2; ++mf) acc[mf][nf] = mfma_bf16(a[mf], b, acc[mf][nf]);
      }
    }
#pragma unroll
    for (int mf = 0; mf < 2; ++mf)
#pragma unroll
      for (int nf = 0; nf < 4; ++nf)
#pragma unroll
        for (int r = 0; r < 4; ++r) {
          const int i = m_base + mf * 16 + rr + r;
          const int j = wid * 64 + nf * 16 + r0;
          const float dSi = exp2f(128.f * log2f(alpha[h * 128 + i]));
          const float val = acc[mf][nf][r] + kvs[(size_t)h * 16384 + i * 128 + j] * dSi;
          out[524288 + (size_t)h * 16384 + i * 128 + j] = val;
        }
  }
}

extern "C" void kernel_launch(void* const* d_in, const int* in_sizes, int n_in,
                              void* d_out, int out_size, void* d_ws, size_t ws_size,
                              hipStream_t stream) {
  const float* x = (const float*)d_in[0];      // (128, 4096)
  const float* W = (const float*)d_in[1];      // (12288, 4096)
  const float* alpha = (const float*)d_in[2];  // (32, 128)
  const float* kvs = (const float*)d_in[3];    // (32, 128, 128)
  float* out = (float*)d_out;

  char* ws = (char*)d_ws;
  __bf16* xb = (__bf16*)ws;                      // 1 MB
  __bf16* qd = (__bf16*)(ws + (1u << 20));       // 1 MB each
  __bf16* kd = (__bf16*)(ws + 2u * (1u << 20));
  __bf16* kdT = (__bf16*)(ws + 3u * (1u << 20));
  __bf16* vT = (__bf16*)(ws + 4u * (1u << 20));
  __bf16* kvsT = (__bf16*)(ws + 5u * (1u << 20));
  float* P = (float*)(ws + 6u * (1u << 20));     // KS * 6,291,456 B

  const size_t pbytes = ws_size > 6u * (1u << 20) ? ws_size - 6u * (1u << 20) : 0;
  int KS = 1;
  while (KS < 4 && (size_t)(KS * 2) * 6291456ull <= pbytes) KS *= 2;
  const int kc_len = 4096 / KS;

  prep_kernel<<<384, 256, 0, stream>>>(x, xb, kvs, alpha, kvsT);
  gemm_split_kernel<<<192 * KS, 256, 0, stream>>>(xb, W, P, kc_len);
  reduce_kernel<<<384, 256, 0, stream>>>(P, alpha, qd, kd, kdT, vT, KS);
  heads_kernel<<<256, 128, 0, stream>>>(qd, kd, kdT, vT, kvsT, kvs, alpha, out);
}

// Round 9
// 70.493 us; speedup vs baseline: 1.3467x; 1.3467x over previous
//
#include <hip/hip_runtime.h>
#include <hip/hip_bf16.h>

// EDMultiheadRetention: S=128, D=4096, H=32, hd=128
// Pipeline: prep (cast x + kvsT) -> gemm_fused (KS=1, 192x512, counted-vmcnt,
//           epilogue applies decay + writes qd/kd/kdT/vT bf16 directly) -> heads

typedef __bf16 bf16x8 __attribute__((ext_vector_type(8)));
typedef float f32x4 __attribute__((ext_vector_type(4)));

typedef __attribute__((address_space(1))) const unsigned g_u32;
typedef __attribute__((address_space(3))) unsigned l_u32;

static __device__ __forceinline__ f32x4 mfma_bf16(bf16x8 a, bf16x8 b, f32x4 c) {
  return __builtin_amdgcn_mfma_f32_16x16x32_bf16(a, b, c, 0, 0, 0);
}

static __device__ __forceinline__ bf16x8 cvt8(float4 lo, float4 hi) {
  return (bf16x8){(__bf16)lo.x, (__bf16)lo.y, (__bf16)lo.z, (__bf16)lo.w,
                  (__bf16)hi.x, (__bf16)hi.y, (__bf16)hi.z, (__bf16)hi.w};
}

#define WAIT_VM0() asm volatile("s_waitcnt vmcnt(0)" ::: "memory")
#define WAIT_VM2() asm volatile("s_waitcnt vmcnt(2)" ::: "memory")
#define WAIT_VM4() asm volatile("s_waitcnt vmcnt(4)" ::: "memory")
#define WAIT_LGKM0() asm volatile("s_waitcnt lgkmcnt(0)" ::: "memory")
#define SCHED_FENCE() __builtin_amdgcn_sched_barrier(0)

// ---------------- kernel 1: cast x -> bf16 (blocks 0..255), kvsT prep (256..383)
__global__ __launch_bounds__(256) void prep_kernel(const float* __restrict__ x,
                                                   __bf16* __restrict__ xb,
                                                   const float* __restrict__ kvs,
                                                   const float* __restrict__ alpha,
                                                   __bf16* __restrict__ kvsT) {
  __shared__ float lds[32][129];
  const int tid = threadIdx.x;
  if (blockIdx.x < 256) {
    const int i = (blockIdx.x * 256 + tid) * 8;
    float4 a = *(const float4*)(x + i);
    float4 b = *(const float4*)(x + i + 4);
    *(bf16x8*)(xb + i) = cvt8(a, b);
    return;
  }
  const int bid = blockIdx.x - 256;
  const int h = bid >> 2, dq = bid & 3;
  const int j = tid & 127, dg = tid >> 7;
  const int d0 = dq * 32;
#pragma unroll
  for (int i = 0; i < 16; ++i) {
    const int dloc = dg * 16 + i;
    const int d = d0 + dloc;
    const float dS = exp2f(128.f * log2f(alpha[h * 128 + d]));
    lds[dloc][j] = kvs[(size_t)h * 16384 + d * 128 + j] * dS;
  }
  __syncthreads();
  const int jj = tid >> 1, dh = tid & 1;
  bf16x8 a0, a1;
#pragma unroll
  for (int i = 0; i < 8; ++i) a0[i] = (__bf16)lds[dh * 16 + i][jj];
#pragma unroll
  for (int i = 0; i < 8; ++i) a1[i] = (__bf16)lds[dh * 16 + 8 + i][jj];
  *(bf16x8*)(kvsT + (size_t)h * 16384 + jj * 128 + d0 + dh * 16) = a0;
  *(bf16x8*)(kvsT + (size_t)h * 16384 + jj * 128 + d0 + dh * 16 + 8) = a1;
}

// ---------------- kernel 2: single-pass GEMM + fused decay/layout epilogue ---
// 192 blocks x 512 thr (8 waves: 4 wm x 2 wn). Tile M=128 x N=64, K=4096, BK=64.
// A: global_load_lds, XOR-swizzled, dbuf, 1 iter ahead. W: f32 regs 2 ahead,
// cvt->ds_write 1 ahead. Counted vmcnt keeps W(T+2) in flight across barriers.
// Epilogue: acc -> LDS(f32) -> decay -> qd/kd ([h][s][d]) and kdT/vT ([h][d][s]).
__global__ __launch_bounds__(512, 2) void gemm_fused_kernel(const __bf16* __restrict__ xb,
                                                            const float* __restrict__ W,
                                                            const float* __restrict__ alpha,
                                                            __bf16* __restrict__ qd,
                                                            __bf16* __restrict__ kd,
                                                            __bf16* __restrict__ kdT,
                                                            __bf16* __restrict__ vT) {
  __shared__ __bf16 Ald[2][128 * 64];  // 32 KB
  __shared__ __bf16 Bld[2][64 * 64];   // 16 KB

  const int tid = threadIdx.x;
  const int wid = tid >> 6, lane = tid & 63;
  const int r0 = lane & 15, l4 = lane >> 4, rr = l4 << 2;
  const int n0 = blockIdx.x * 64;
  const int wm = wid & 3, wn = wid >> 2;

  // A staging: 2 DMA units/thread; unit u -> (row=u>>3, phys chunk p=u&7),
  // source logical chunk g = p ^ (row&7); LDS dest linear (u*16 B).
  int a_row[2], a_koff[2];
#pragma unroll
  for (int i = 0; i < 2; ++i) {
    const int u = i * 512 + tid;
    a_row[i] = u >> 3;
    a_koff[i] = ((u & 7) ^ (a_row[i] & 7)) << 3;
  }
  // B staging: 1 unit/thread (64 rows x 8 chunks = 512 units)
  const int b_row = tid >> 3, b_p = tid & 7;
  const int b_elem = b_row * 64 + b_p * 8;
  const float* wp = W + (size_t)(n0 + b_row) * 4096 + ((b_p ^ (b_row & 7)) << 3);

  // fragment read offsets (elements): logical chunk c = kh*4+l4, phys = c^(row&7)
  int a_off[2][2], b_off[2][2];
#pragma unroll
  for (int mf = 0; mf < 2; ++mf)
#pragma unroll
    for (int kh = 0; kh < 2; ++kh) {
      const int row = wm * 32 + mf * 16 + r0;
      const int p = (kh * 4 + l4) ^ (row & 7);
      a_off[mf][kh] = row * 64 + p * 8;
    }
#pragma unroll
  for (int nf = 0; nf < 2; ++nf)
#pragma unroll
    for (int kh = 0; kh < 2; ++kh) {
      const int row = wn * 32 + nf * 16 + r0;
      const int p = (kh * 4 + l4) ^ (row & 7);
      b_off[nf][kh] = row * 64 + p * 8;
    }

  f32x4 acc[2][2];
#pragma unroll
  for (int mf = 0; mf < 2; ++mf)
#pragma unroll
    for (int nf = 0; nf < 2; ++nf) acc[mf][nf] = (f32x4){0.f, 0.f, 0.f, 0.f};

  float4 w0lo, w0hi, w1lo, w1hi;  // W reg sets: set[T&1] holds W(T)

#define A_ISSUE(T_, BUF_)                                                        \
  do {                                                                           \
    const int kb_ = (T_) * 64;                                                   \
    char* dst_ = (char*)&Ald[0][0] + (BUF_) * 16384;                             \
    _Pragma("unroll") for (int i = 0; i < 2; ++i) {                              \
      const __bf16* src = xb + a_row[i] * 4096 + kb_ + a_koff[i];                \
      __builtin_amdgcn_global_load_lds((g_u32*)(const void*)src,                 \
          (l_u32*)(void*)(dst_ + i * 8192 + wid * 1024), 16, 0, 0);              \
    }                                                                            \
  } while (0)

  // ---- prologue: A(0)->buf0; W(0)->set0; W(1)->set1; B(0) from set0
  A_ISSUE(0, 0);
  w0lo = *(const float4*)(wp);
  w0hi = *(const float4*)(wp + 4);
  w1lo = *(const float4*)(wp + 64);
  w1hi = *(const float4*)(wp + 64 + 4);
  WAIT_VM2();  // A(0)+W(0) done; W(1) in flight
  *(bf16x8*)(&Bld[0][b_elem]) = cvt8(w0lo, w0hi);
  WAIT_LGKM0();
  SCHED_FENCE();
  __builtin_amdgcn_s_barrier();
  SCHED_FENCE();

// Iter T: issue A(T+1)->buf 1-CUR, W(T+2)->LD set; compute from buf CUR;
// then wait W(T+1), ds_write B(T+1) from WR set; wait A(T+1); barrier.
#define GEMM_ITER(T, CUR, WRLO, WRHI, LDLO, LDHI)                                \
  do {                                                                           \
    const bool hn1 = (T) + 1 < 64, hn2 = (T) + 2 < 64;                           \
    if (hn1) A_ISSUE((T) + 1, 1 - (CUR));                                        \
    if (hn2) {                                                                   \
      const int kb = ((T) + 2) * 64;                                             \
      LDLO = *(const float4*)(wp + kb);                                          \
      LDHI = *(const float4*)(wp + kb + 4);                                      \
    }                                                                            \
    SCHED_FENCE();                                                               \
    bf16x8 af[2][2], bfr[2][2];                                                  \
    _Pragma("unroll") for (int kh = 0; kh < 2; ++kh) {                           \
      _Pragma("unroll") for (int mf = 0; mf < 2; ++mf)                           \
          af[mf][kh] = *(const bf16x8*)(&Ald[CUR][a_off[mf][kh]]);               \
      _Pragma("unroll") for (int nf = 0; nf < 2; ++nf)                           \
          bfr[nf][kh] = *(const bf16x8*)(&Bld[CUR][b_off[nf][kh]]);              \
    }                                                                            \
    _Pragma("unroll") for (int kh = 0; kh < 2; ++kh)                             \
        _Pragma("unroll") for (int mf = 0; mf < 2; ++mf)                         \
            _Pragma("unroll") for (int nf = 0; nf < 2; ++nf)                     \
                acc[mf][nf] = mfma_bf16(af[mf][kh], bfr[nf][kh], acc[mf][nf]);   \
    SCHED_FENCE();                                                               \
    if (hn1) {                                                                   \
      if (hn2) { WAIT_VM4(); } else { WAIT_VM2(); } /* W(T+1) landed */          \
      *(bf16x8*)(&Bld[1 - (CUR)][b_elem]) = cvt8(WRLO, WRHI);                    \
      if (hn2) { WAIT_VM2(); } else { WAIT_VM0(); } /* A(T+1) landed */          \
      WAIT_LGKM0();                                                              \
      SCHED_FENCE();                                                             \
      __builtin_amdgcn_s_barrier();                                              \
      SCHED_FENCE();                                                             \
    }                                                                            \
  } while (0)

  for (int t = 0; t < 64; t += 2) {
    GEMM_ITER(t, 0, w1lo, w1hi, w0lo, w0hi);
    GEMM_ITER(t + 1, 1, w0lo, w0hi, w1lo, w1hi);
  }
#undef GEMM_ITER
#undef A_ISSUE

  // ---- fused epilogue: acc -> LDS f32 -> decay -> bf16 layouts
  __syncthreads();  // all A/B LDS reads done; safe to repurpose Ald
  float* LDSf = (float*)&Ald[0][0];  // 128 x 64 f32 = 32 KB
#pragma unroll
  for (int mf = 0; mf < 2; ++mf)
#pragma unroll
    for (int nf = 0; nf < 2; ++nf)
#pragma unroll
      for (int r = 0; r < 4; ++r) {
        const int s = wm * 32 + mf * 16 + rr + r;
        const int c = wn * 32 + nf * 16 + r0;
        LDSf[s * 64 + c] = acc[mf][nf][r];
      }
  __syncthreads();

  const int which = n0 >> 12;      // 0=q 1=k 2=v
  const int hd = n0 & 4095;
  const int h = hd >> 7;
  const int db = hd & 127;         // 0 or 64

  if (which < 2) {
    // row-major [h][s][db..db+64): unit u = (s, 8d)
    __bf16* dst = (which == 0 ? qd : kd) + (size_t)h * 16384;
#pragma unroll
    for (int i = 0; i < 2; ++i) {
      const int u = i * 512 + tid;
      const int s = u >> 3, d8 = (u & 7) * 8;
      bf16x8 frag;
#pragma unroll
      for (int j = 0; j < 8; ++j) {
        const float la = log2f(alpha[h * 128 + db + d8 + j]);
        const float e = (which == 0) ? (float)(s - 127) : (float)(127 - s);
        frag[j] = (__bf16)(LDSf[s * 64 + d8 + j] * exp2f(e * la - 6.0f));
      }
      *(bf16x8*)(dst + s * 128 + db + d8) = frag;
    }
  }
  if (which >= 1) {
    // transposed [h][db+d][s]: unit u = (d, 8s)
    __bf16* dstT = (which == 1 ? kdT : vT) + (size_t)h * 16384;
#pragma unroll
    for (int i = 0; i < 2; ++i) {
      const int u = i * 512 + tid;
      const int d = u >> 4, s8 = (u & 15) * 8;
      bf16x8 frag;
      if (which == 1) {
        const float la = log2f(alpha[h * 128 + db + d]);
#pragma unroll
        for (int j = 0; j < 8; ++j)
          frag[j] = (__bf16)(LDSf[(s8 + j) * 64 + d] * exp2f((float)(127 - (s8 + j)) * la - 6.0f));
      } else {
#pragma unroll
        for (int j = 0; j < 8; ++j) frag[j] = (__bf16)LDSf[(s8 + j) * 64 + d];
      }
      *(bf16x8*)(dstT + (db + d) * 128 + s8) = frag;
    }
  }
}

// ---------------- kernel 3: per-head retention (all contiguous bf16 loads) --
// bid<128: out rows; bid>=128: new_kvs rows. 128 threads (2 waves).
__global__ __launch_bounds__(128) void heads_kernel(const __bf16* __restrict__ qd,
                                                    const __bf16* __restrict__ kd,
                                                    const __bf16* __restrict__ kdT,
                                                    const __bf16* __restrict__ vT,
                                                    const __bf16* __restrict__ kvsT,
                                                    const float* __restrict__ kvs,
                                                    const float* __restrict__ alpha,
                                                    float* __restrict__ out) {
  const int bid = blockIdx.x;
  const int tid = threadIdx.x;
  const int wid = tid >> 6, lane = tid & 63;
  const int r0 = lane & 15, l4 = lane >> 4;
  const int g8 = l4 << 3, rr = l4 << 2;

  if (bid < 128) {
    const int h = bid >> 2, w = bid & 3;
    const int m_base = w * 32;
    __shared__ __bf16 attn_s[32][136];
    const __bf16* qh = qd + (size_t)h * 16384;
    const __bf16* kh = kd + (size_t)h * 16384;

    f32x4 acc[2][4];
#pragma unroll
    for (int mf = 0; mf < 2; ++mf)
#pragma unroll
      for (int nf = 0; nf < 4; ++nf) acc[mf][nf] = (f32x4){0.f, 0.f, 0.f, 0.f};

    // phase 1: attn cols wid*64..+64
#pragma unroll
    for (int k0 = 0; k0 < 128; k0 += 32) {
      const int kk = k0 + g8;
      bf16x8 a[2];
#pragma unroll
      for (int mf = 0; mf < 2; ++mf)
        a[mf] = *(const bf16x8*)(qh + (m_base + mf * 16 + r0) * 128 + kk);
#pragma unroll
      for (int nf = 0; nf < 4; ++nf) {
        const int jn = wid * 64 + nf * 16 + r0;
        bf16x8 b = *(const bf16x8*)(kh + jn * 128 + kk);
#pragma unroll
        for (int mf = 0; mf < 2; ++mf) acc[mf][nf] = mfma_bf16(a[mf], b, acc[mf][nf]);
      }
    }
#pragma unroll
    for (int mf = 0; mf < 2; ++mf)
#pragma unroll
      for (int nf = 0; nf < 4; ++nf)
#pragma unroll
        for (int r = 0; r < 4; ++r) {
          const int i = m_base + mf * 16 + rr + r;
          const int j = wid * 64 + nf * 16 + r0;
          attn_s[mf * 16 + rr + r][j] = (__bf16)((j <= i) ? acc[mf][nf][r] : 0.f);
        }
    __syncthreads();

    // phase 2: out = gelu(attn @ v + q @ kvsT), d2 in wid*64..+64
#pragma unroll
    for (int mf = 0; mf < 2; ++mf)
#pragma unroll
      for (int nf = 0; nf < 4; ++nf) acc[mf][nf] = (f32x4){0.f, 0.f, 0.f, 0.f};
    const __bf16* vTh = vT + (size_t)h * 16384;
    const __bf16* kvsTh = kvsT + (size_t)h * 16384;
#pragma unroll
    for (int k0 = 0; k0 < 128; k0 += 32) {
      const int kk = k0 + g8;
      bf16x8 a[2];
#pragma unroll
      for (int mf = 0; mf < 2; ++mf)
        a[mf] = *(const bf16x8*)(&attn_s[mf * 16 + r0][kk]);
#pragma unroll
      for (int nf = 0; nf < 4; ++nf) {
        const int d2 = wid * 64 + nf * 16 + r0;
        bf16x8 b = *(const bf16x8*)(vTh + d2 * 128 + kk);
#pragma unroll
        for (int mf = 0; mf < 2; ++mf) acc[mf][nf] = mfma_bf16(a[mf], b, acc[mf][nf]);
      }
    }
#pragma unroll
    for (int k0 = 0; k0 < 128; k0 += 32) {
      const int kk = k0 + g8;
      bf16x8 a[2];
#pragma unroll
      for (int mf = 0; mf < 2; ++mf)
        a[mf] = *(const bf16x8*)(qh + (m_base + mf * 16 + r0) * 128 + kk);
#pragma unroll
      for (int nf = 0; nf < 4; ++nf) {
        const int d2 = wid * 64 + nf * 16 + r0;
        bf16x8 b = *(const bf16x8*)(kvsTh + d2 * 128 + kk);
#pragma unroll
        for (int mf = 0; mf < 2; ++mf) acc[mf][nf] = mfma_bf16(a[mf], b, acc[mf][nf]);
      }
    }
#pragma unroll
    for (int mf = 0; mf < 2; ++mf)
#pragma unroll
      for (int nf = 0; nf < 4; ++nf)
#pragma unroll
        for (int r = 0; r < 4; ++r) {
          const int s = m_base + mf * 16 + rr + r;
          const int d2 = wid * 64 + nf * 16 + r0;
          const float y = acc[mf][nf][r];
          const float u = 0.7978845608028654f * (y + 0.044715f * y * y * y);
          out[(size_t)s * 4096 + h * 128 + d2] = 0.5f * y * (1.f + tanhf(u));
        }
  } else {
    const int b2 = bid - 128;
    const int h = b2 >> 2, w = b2 & 3;
    const int m_base = w * 32;
    const __bf16* kTh = kdT + (size_t)h * 16384;
    const __bf16* vTh = vT + (size_t)h * 16384;

    f32x4 acc[2][4];
#pragma unroll
    for (int mf = 0; mf < 2; ++mf)
#pragma unroll
      for (int nf = 0; nf < 4; ++nf) acc[mf][nf] = (f32x4){0.f, 0.f, 0.f, 0.f};
#pragma unroll
    for (int k0 = 0; k0 < 128; k0 += 32) {
      const int kk = k0 + g8;
      bf16x8 a[2];
#pragma unroll
      for (int mf = 0; mf < 2; ++mf)
        a[mf] = *(const bf16x8*)(kTh + (m_base + mf * 16 + r0) * 128 + kk);
#pragma unroll
      for (int nf = 0; nf < 4; ++nf) {
        const int j = wid * 64 + nf * 16 + r0;
        bf16x8 b = *(const bf16x8*)(vTh + j * 128 + kk);
#pragma unroll
        for (int mf = 0; mf < 2; ++mf) acc[mf][nf] = mfma_bf16(a[mf], b, acc[mf][nf]);
      }
    }
#pragma unroll
    for (int mf = 0; mf < 2; ++mf)
#pragma unroll
      for (int nf = 0; nf < 4; ++nf)
#pragma unroll
        for (int r = 0; r < 4; ++r) {
          const int i = m_base + mf * 16 + rr + r;
          const int j = wid * 64 + nf * 16 + r0;
          const float dSi = exp2f(128.f * log2f(alpha[h * 128 + i]));
          const float val = acc[mf][nf][r] + kvs[(size_t)h * 16384 + i * 128 + j] * dSi;
          out[524288 + (size_t)h * 16384 + i * 128 + j] = val;
        }
  }
}

extern "C" void kernel_launch(void* const* d_in, const int* in_sizes, int n_in,
                              void* d_out, int out_size, void* d_ws, size_t ws_size,
                              hipStream_t stream) {
  const float* x = (const float*)d_in[0];      // (128, 4096)
  const float* W = (const float*)d_in[1];      // (12288, 4096)
  const float* alpha = (const float*)d_in[2];  // (32, 128)
  const float* kvs = (const float*)d_in[3];    // (32, 128, 128)
  float* out = (float*)d_out;

  char* ws = (char*)d_ws;
  __bf16* xb = (__bf16*)ws;                      // 1 MB
  __bf16* qd = (__bf16*)(ws + (1u << 20));       // 1 MB each
  __bf16* kd = (__bf16*)(ws + 2u * (1u << 20));
  __bf16* kdT = (__bf16*)(ws + 3u * (1u << 20));
  __bf16* vT = (__bf16*)(ws + 4u * (1u << 20));
  __bf16* kvsT = (__bf16*)(ws + 5u * (1u << 20));

  prep_kernel<<<384, 256, 0, stream>>>(x, xb, kvs, alpha, kvsT);
  gemm_fused_kernel<<<192, 512, 0, stream>>>(xb, W, alpha, qd, kd, kdT, vT);
  heads_kernel<<<256, 128, 0, stream>>>(qd, kd, kdT, vT, kvsT, kvs, alpha, out);
}

// Round 10
// 67.868 us; speedup vs baseline: 1.3988x; 1.0387x over previous
//
#include <hip/hip_runtime.h>
#include <hip/hip_bf16.h>

// EDMultiheadRetention: S=128, D=4096, H=32, hd=128
// Pipeline: prep (cast x + kvsT) -> gemm_fused (KS=1, 192x512; A 3-buf 2-ahead,
//           W regs 2-ahead, single vmcnt(4) wait/iter; fused decay epilogue) -> heads

typedef __bf16 bf16x8 __attribute__((ext_vector_type(8)));
typedef float f32x4 __attribute__((ext_vector_type(4)));

typedef __attribute__((address_space(1))) const unsigned g_u32;
typedef __attribute__((address_space(3))) unsigned l_u32;

static __device__ __forceinline__ f32x4 mfma_bf16(bf16x8 a, bf16x8 b, f32x4 c) {
  return __builtin_amdgcn_mfma_f32_16x16x32_bf16(a, b, c, 0, 0, 0);
}

static __device__ __forceinline__ bf16x8 cvt8(float4 lo, float4 hi) {
  return (bf16x8){(__bf16)lo.x, (__bf16)lo.y, (__bf16)lo.z, (__bf16)lo.w,
                  (__bf16)hi.x, (__bf16)hi.y, (__bf16)hi.z, (__bf16)hi.w};
}

#define WAIT_VM0() asm volatile("s_waitcnt vmcnt(0)" ::: "memory")
#define WAIT_VM4() asm volatile("s_waitcnt vmcnt(4)" ::: "memory")
#define WAIT_LGKM0() asm volatile("s_waitcnt lgkmcnt(0)" ::: "memory")
#define SCHED_FENCE() __builtin_amdgcn_sched_barrier(0)

// ---------------- kernel 1: cast x -> bf16 (blocks 0..255), kvsT prep (256..383)
__global__ __launch_bounds__(256) void prep_kernel(const float* __restrict__ x,
                                                   __bf16* __restrict__ xb,
                                                   const float* __restrict__ kvs,
                                                   const float* __restrict__ alpha,
                                                   __bf16* __restrict__ kvsT) {
  __shared__ float lds[32][129];
  const int tid = threadIdx.x;
  if (blockIdx.x < 256) {
    const int i = (blockIdx.x * 256 + tid) * 8;
    float4 a = *(const float4*)(x + i);
    float4 b = *(const float4*)(x + i + 4);
    *(bf16x8*)(xb + i) = cvt8(a, b);
    return;
  }
  const int bid = blockIdx.x - 256;
  const int h = bid >> 2, dq = bid & 3;
  const int j = tid & 127, dg = tid >> 7;
  const int d0 = dq * 32;
#pragma unroll
  for (int i = 0; i < 16; ++i) {
    const int dloc = dg * 16 + i;
    const int d = d0 + dloc;
    const float dS = exp2f(128.f * log2f(alpha[h * 128 + d]));
    lds[dloc][j] = kvs[(size_t)h * 16384 + d * 128 + j] * dS;
  }
  __syncthreads();
  const int jj = tid >> 1, dh = tid & 1;
  bf16x8 a0, a1;
#pragma unroll
  for (int i = 0; i < 8; ++i) a0[i] = (__bf16)lds[dh * 16 + i][jj];
#pragma unroll
  for (int i = 0; i < 8; ++i) a1[i] = (__bf16)lds[dh * 16 + 8 + i][jj];
  *(bf16x8*)(kvsT + (size_t)h * 16384 + jj * 128 + d0 + dh * 16) = a0;
  *(bf16x8*)(kvsT + (size_t)h * 16384 + jj * 128 + d0 + dh * 16 + 8) = a1;
}

// ---------------- kernel 2: single-pass GEMM + fused decay/layout epilogue ---
// 192 blocks x 512 thr (8 waves: 4 wm x 2 wn). Tile M=128 x N=64, K=4096, BK=64.
// A: global_load_lds, XOR-swizzled, 3 buffers, issued 2 iters ahead.
// W: f32 regs, issued 2 iters ahead; cvt->ds_write 1 iter ahead.
// Steady state: one vmcnt(4) per iter drains A(T+1)+W(T+1), keeps T+2 in flight.
__global__ __launch_bounds__(512, 2) void gemm_fused_kernel(const __bf16* __restrict__ xb,
                                                            const float* __restrict__ W,
                                                            const float* __restrict__ alpha,
                                                            __bf16* __restrict__ qd,
                                                            __bf16* __restrict__ kd,
                                                            __bf16* __restrict__ kdT,
                                                            __bf16* __restrict__ vT) {
  __shared__ __bf16 Ald[3][128 * 64];  // 48 KB
  __shared__ __bf16 Bld[2][64 * 64];   // 16 KB

  const int tid = threadIdx.x;
  const int wid = tid >> 6, lane = tid & 63;
  const int r0 = lane & 15, l4 = lane >> 4, rr = l4 << 2;
  const int n0 = blockIdx.x * 64;
  const int wm = wid & 3, wn = wid >> 2;

  // A staging: 2 DMA units/thread; unit u -> (row=u>>3, phys chunk p=u&7),
  // source logical chunk g = p ^ (row&7); LDS dest linear (u*16 B).
  int a_row[2], a_koff[2];
#pragma unroll
  for (int i = 0; i < 2; ++i) {
    const int u = i * 512 + tid;
    a_row[i] = u >> 3;
    a_koff[i] = ((u & 7) ^ (a_row[i] & 7)) << 3;
  }
  // B staging: 1 unit/thread (64 rows x 8 chunks = 512 units)
  const int b_row = tid >> 3, b_p = tid & 7;
  const int b_elem = b_row * 64 + b_p * 8;
  const float* wp = W + (size_t)(n0 + b_row) * 4096 + ((b_p ^ (b_row & 7)) << 3);

  // fragment read offsets (elements): logical chunk c = kh*4+l4, phys = c^(row&7)
  int a_off[2][2], b_off[2][2];
#pragma unroll
  for (int mf = 0; mf < 2; ++mf)
#pragma unroll
    for (int kh = 0; kh < 2; ++kh) {
      const int row = wm * 32 + mf * 16 + r0;
      const int p = (kh * 4 + l4) ^ (row & 7);
      a_off[mf][kh] = row * 64 + p * 8;
    }
#pragma unroll
  for (int nf = 0; nf < 2; ++nf)
#pragma unroll
    for (int kh = 0; kh < 2; ++kh) {
      const int row = wn * 32 + nf * 16 + r0;
      const int p = (kh * 4 + l4) ^ (row & 7);
      b_off[nf][kh] = row * 64 + p * 8;
    }

  f32x4 acc[2][2];
#pragma unroll
  for (int mf = 0; mf < 2; ++mf)
#pragma unroll
    for (int nf = 0; nf < 2; ++nf) acc[mf][nf] = (f32x4){0.f, 0.f, 0.f, 0.f};

  float4 w0lo, w0hi, w1lo, w1hi;  // set[T&1] holds W(T) until its ds_write

#define A_ISSUE(T_, BUF_)                                                        \
  do {                                                                           \
    const int kb_ = (T_) * 64;                                                   \
    char* dst_ = (char*)&Ald[0][0] + (BUF_) * 16384;                             \
    _Pragma("unroll") for (int i = 0; i < 2; ++i) {                              \
      const __bf16* src = xb + a_row[i] * 4096 + kb_ + a_koff[i];                \
      __builtin_amdgcn_global_load_lds((g_u32*)(const void*)src,                 \
          (l_u32*)(void*)(dst_ + i * 8192 + wid * 1024), 16, 0, 0);              \
    }                                                                            \
  } while (0)

  // ---- prologue. Issue order (FIFO): A(0), W(0), A(1), W(1).
  A_ISSUE(0, 0);
  w0lo = *(const float4*)(wp);
  w0hi = *(const float4*)(wp + 4);
  A_ISSUE(1, 1);
  w1lo = *(const float4*)(wp + 64);
  w1hi = *(const float4*)(wp + 64 + 4);
  WAIT_VM4();  // A(0)+W(0) done; A(1)+W(1) in flight
  *(bf16x8*)(&Bld[0][b_elem]) = cvt8(w0lo, w0hi);
  WAIT_LGKM0();
  SCHED_FENCE();
  __builtin_amdgcn_s_barrier();
  SCHED_FENCE();

// Iter T: issue A(T+2)->BUFN2 and W(T+2)->LD set; compute from BUFC/Bld[CURB];
// wait vmcnt(4) (A(T+1)+W(T+1) landed, T+2 stays in flight); ds_write B(T+1); barrier.
#define GEMM_ITER(T, BUFC, BUFN2, CURB, WRLO, WRHI, LDLO, LDHI)                  \
  do {                                                                           \
    const bool hn1 = (T) + 1 < 64, hn2 = (T) + 2 < 64;                           \
    if (hn2) {                                                                   \
      A_ISSUE((T) + 2, BUFN2);                                                   \
      const int kb = ((T) + 2) * 64;                                             \
      LDLO = *(const float4*)(wp + kb);                                          \
      LDHI = *(const float4*)(wp + kb + 4);                                      \
    }                                                                            \
    SCHED_FENCE();                                                               \
    const __bf16* abase_ = &Ald[0][0] + (BUFC) * 8192;                           \
    bf16x8 af[2][2], bfr[2][2];                                                  \
    _Pragma("unroll") for (int kh = 0; kh < 2; ++kh) {                           \
      _Pragma("unroll") for (int mf = 0; mf < 2; ++mf)                           \
          af[mf][kh] = *(const bf16x8*)(abase_ + a_off[mf][kh]);                 \
      _Pragma("unroll") for (int nf = 0; nf < 2; ++nf)                           \
          bfr[nf][kh] = *(const bf16x8*)(&Bld[CURB][b_off[nf][kh]]);             \
    }                                                                            \
    _Pragma("unroll") for (int kh = 0; kh < 2; ++kh)                             \
        _Pragma("unroll") for (int mf = 0; mf < 2; ++mf)                         \
            _Pragma("unroll") for (int nf = 0; nf < 2; ++nf)                     \
                acc[mf][nf] = mfma_bf16(af[mf][kh], bfr[nf][kh], acc[mf][nf]);   \
    SCHED_FENCE();                                                               \
    if (hn1) {                                                                   \
      if (hn2) { WAIT_VM4(); } else { WAIT_VM0(); } /* A,W(T+1) landed */        \
      *(bf16x8*)(&Bld[1 - (CURB)][b_elem]) = cvt8(WRLO, WRHI);                   \
      WAIT_LGKM0();                                                              \
      SCHED_FENCE();                                                             \
      __builtin_amdgcn_s_barrier();                                              \
      SCHED_FENCE();                                                             \
    }                                                                            \
  } while (0)

  {
    int bA = 0;  // buffer holding A(t) at even-iter entry
    for (int t = 0; t < 64; t += 2) {
      int bB = bA + 1; if (bB >= 3) bB = 0;  // holds A(t+1)
      int bC = bB + 1; if (bC >= 3) bC = 0;  // free -> receives A(t+2)
      GEMM_ITER(t, bA, bC, 0, w1lo, w1hi, w0lo, w0hi);
      GEMM_ITER(t + 1, bB, bA, 1, w0lo, w0hi, w1lo, w1hi);  // A(t+3) -> bA
      bA = bC;
    }
  }
#undef GEMM_ITER
#undef A_ISSUE

  // ---- fused epilogue: acc -> LDS f32 -> decay -> bf16 layouts
  __syncthreads();  // all A/B LDS reads done; safe to repurpose Ald
  float* LDSf = (float*)&Ald[0][0];  // 128 x 64 f32 = 32 KB
#pragma unroll
  for (int mf = 0; mf < 2; ++mf)
#pragma unroll
    for (int nf = 0; nf < 2; ++nf)
#pragma unroll
      for (int r = 0; r < 4; ++r) {
        const int s = wm * 32 + mf * 16 + rr + r;
        const int c = wn * 32 + nf * 16 + r0;
        LDSf[s * 64 + c] = acc[mf][nf][r];
      }
  __syncthreads();

  const int which = n0 >> 12;      // 0=q 1=k 2=v
  const int hd = n0 & 4095;
  const int h = hd >> 7;
  const int db = hd & 127;         // 0 or 64

  if (which < 2) {
    // row-major [h][s][db..db+64): unit u = (s, 8d)
    __bf16* dst = (which == 0 ? qd : kd) + (size_t)h * 16384;
#pragma unroll
    for (int i = 0; i < 2; ++i) {
      const int u = i * 512 + tid;
      const int s = u >> 3, d8 = (u & 7) * 8;
      bf16x8 frag;
#pragma unroll
      for (int j = 0; j < 8; ++j) {
        const float la = log2f(alpha[h * 128 + db + d8 + j]);
        const float e = (which == 0) ? (float)(s - 127) : (float)(127 - s);
        frag[j] = (__bf16)(LDSf[s * 64 + d8 + j] * exp2f(e * la - 6.0f));
      }
      *(bf16x8*)(dst + s * 128 + db + d8) = frag;
    }
  }
  if (which >= 1) {
    // transposed [h][db+d][s]: unit u = (d, 8s)
    __bf16* dstT = (which == 1 ? kdT : vT) + (size_t)h * 16384;
#pragma unroll
    for (int i = 0; i < 2; ++i) {
      const int u = i * 512 + tid;
      const int d = u >> 4, s8 = (u & 15) * 8;
      bf16x8 frag;
      if (which == 1) {
        const float la = log2f(alpha[h * 128 + db + d]);
#pragma unroll
        for (int j = 0; j < 8; ++j)
          frag[j] = (__bf16)(LDSf[(s8 + j) * 64 + d] * exp2f((float)(127 - (s8 + j)) * la - 6.0f));
      } else {
#pragma unroll
        for (int j = 0; j < 8; ++j) frag[j] = (__bf16)LDSf[(s8 + j) * 64 + d];
      }
      *(bf16x8*)(dstT + (db + d) * 128 + s8) = frag;
    }
  }
}

// ---------------- kernel 3: per-head retention (all contiguous bf16 loads) --
// bid<128: out rows; bid>=128: new_kvs rows. 128 threads (2 waves).
__global__ __launch_bounds__(128) void heads_kernel(const __bf16* __restrict__ qd,
                                                    const __bf16* __restrict__ kd,
                                                    const __bf16* __restrict__ kdT,
                                                    const __bf16* __restrict__ vT,
                                                    const __bf16* __restrict__ kvsT,
                                                    const float* __restrict__ kvs,
                                                    const float* __restrict__ alpha,
                                                    float* __restrict__ out) {
  const int bid = blockIdx.x;
  const int tid = threadIdx.x;
  const int wid = tid >> 6, lane = tid & 63;
  const int r0 = lane & 15, l4 = lane >> 4;
  const int g8 = l4 << 3, rr = l4 << 2;

  if (bid < 128) {
    const int h = bid >> 2, w = bid & 3;
    const int m_base = w * 32;
    __shared__ __bf16 attn_s[32][136];
    const __bf16* qh = qd + (size_t)h * 16384;
    const __bf16* kh = kd + (size_t)h * 16384;

    f32x4 acc[2][4];
#pragma unroll
    for (int mf = 0; mf < 2; ++mf)
#pragma unroll
      for (int nf = 0; nf < 4; ++nf) acc[mf][nf] = (f32x4){0.f, 0.f, 0.f, 0.f};

    // phase 1: attn cols wid*64..+64
#pragma unroll
    for (int k0 = 0; k0 < 128; k0 += 32) {
      const int kk = k0 + g8;
      bf16x8 a[2];
#pragma unroll
      for (int mf = 0; mf < 2; ++mf)
        a[mf] = *(const bf16x8*)(qh + (m_base + mf * 16 + r0) * 128 + kk);
#pragma unroll
      for (int nf = 0; nf < 4; ++nf) {
        const int jn = wid * 64 + nf * 16 + r0;
        bf16x8 b = *(const bf16x8*)(kh + jn * 128 + kk);
#pragma unroll
        for (int mf = 0; mf < 2; ++mf) acc[mf][nf] = mfma_bf16(a[mf], b, acc[mf][nf]);
      }
    }
#pragma unroll
    for (int mf = 0; mf < 2; ++mf)
#pragma unroll
      for (int nf = 0; nf < 4; ++nf)
#pragma unroll
        for (int r = 0; r < 4; ++r) {
          const int i = m_base + mf * 16 + rr + r;
          const int j = wid * 64 + nf * 16 + r0;
          attn_s[mf * 16 + rr + r][j] = (__bf16)((j <= i) ? acc[mf][nf][r] : 0.f);
        }
    __syncthreads();

    // phase 2: out = gelu(attn @ v + q @ kvsT), d2 in wid*64..+64
#pragma unroll
    for (int mf = 0; mf < 2; ++mf)
#pragma unroll
      for (int nf = 0; nf < 4; ++nf) acc[mf][nf] = (f32x4){0.f, 0.f, 0.f, 0.f};
    const __bf16* vTh = vT + (size_t)h * 16384;
    const __bf16* kvsTh = kvsT + (size_t)h * 16384;
#pragma unroll
    for (int k0 = 0; k0 < 128; k0 += 32) {
      const int kk = k0 + g8;
      bf16x8 a[2];
#pragma unroll
      for (int mf = 0; mf < 2; ++mf)
        a[mf] = *(const bf16x8*)(&attn_s[mf * 16 + r0][kk]);
#pragma unroll
      for (int nf = 0; nf < 4; ++nf) {
        const int d2 = wid * 64 + nf * 16 + r0;
        bf16x8 b = *(const bf16x8*)(vTh + d2 * 128 + kk);
#pragma unroll
        for (int mf = 0; mf < 2; ++mf) acc[mf][nf] = mfma_bf16(a[mf], b, acc[mf][nf]);
      }
    }
#pragma unroll
    for (int k0 = 0; k0 < 128; k0 += 32) {
      const int kk = k0 + g8;
      bf16x8 a[2];
#pragma unroll
      for (int mf = 0; mf < 2; ++mf)
        a[mf] = *(const bf16x8*)(qh + (m_base + mf * 16 + r0) * 128 + kk);
#pragma unroll
      for (int nf = 0; nf < 4; ++nf) {
        const int d2 = wid * 64 + nf * 16 + r0;
        bf16x8 b = *(const bf16x8*)(kvsTh + d2 * 128 + kk);
#pragma unroll
        for (int mf = 0; mf < 2; ++mf) acc[mf][nf] = mfma_bf16(a[mf], b, acc[mf][nf]);
      }
    }
#pragma unroll
    for (int mf = 0; mf < 2; ++mf)
#pragma unroll
      for (int nf = 0; nf < 4; ++nf)
#pragma unroll
        for (int r = 0; r < 4; ++r) {
          const int s = m_base + mf * 16 + rr + r;
          const int d2 = wid * 64 + nf * 16 + r0;
          const float y = acc[mf][nf][r];
          const float u = 0.7978845608028654f * (y + 0.044715f * y * y * y);
          out[(size_t)s * 4096 + h * 128 + d2] = 0.5f * y * (1.f + tanhf(u));
        }
  } else {
    const int b2 = bid - 128;
    const int h = b2 >> 2, w = b2 & 3;
    const int m_base = w * 32;
    const __bf16* kTh = kdT + (size_t)h * 16384;
    const __bf16* vTh = vT + (size_t)h * 16384;

    f32x4 acc[2][4];
#pragma unroll
    for (int mf = 0; mf < 2; ++mf)
#pragma unroll
      for (int nf = 0; nf < 4; ++nf) acc[mf][nf] = (f32x4){0.f, 0.f, 0.f, 0.f};
#pragma unroll
    for (int k0 = 0; k0 < 128; k0 += 32) {
      const int kk = k0 + g8;
      bf16x8 a[2];
#pragma unroll
      for (int mf = 0; mf < 2; ++mf)
        a[mf] = *(const bf16x8*)(kTh + (m_base + mf * 16 + r0) * 128 + kk);
#pragma unroll
      for (int nf = 0; nf < 4; ++nf) {
        const int j = wid * 64 + nf * 16 + r0;
        bf16x8 b = *(const bf16x8*)(vTh + j * 128 + kk);
#pragma unroll
        for (int mf = 0; mf < 2; ++mf) acc[mf][nf] = mfma_bf16(a[mf], b, acc[mf][nf]);
      }
    }
#pragma unroll
    for (int mf = 0; mf < 2; ++mf)
#pragma unroll
      for (int nf = 0; nf < 4; ++nf)
#pragma unroll
        for (int r = 0; r < 4; ++r) {
          const int i = m_base + mf * 16 + rr + r;
          const int j = wid * 64 + nf * 16 + r0;
          const float dSi = exp2f(128.f * log2f(alpha[h * 128 + i]));
          const float val = acc[mf][nf][r] + kvs[(size_t)h * 16384 + i * 128 + j] * dSi;
          out[524288 + (size_t)h * 16384 + i * 128 + j] = val;
        }
  }
}

extern "C" void kernel_launch(void* const* d_in, const int* in_sizes, int n_in,
                              void* d_out, int out_size, void* d_ws, size_t ws_size,
                              hipStream_t stream) {
  const float* x = (const float*)d_in[0];      // (128, 4096)
  const float* W = (const float*)d_in[1];      // (12288, 4096)
  const float* alpha = (const float*)d_in[2];  // (32, 128)
  const float* kvs = (const float*)d_in[3];    // (32, 128, 128)
  float* out = (float*)d_out;

  char* ws = (char*)d_ws;
  __bf16* xb = (__bf16*)ws;                      // 1 MB
  __bf16* qd = (__bf16*)(ws + (1u << 20));       // 1 MB each
  __bf16* kd = (__bf16*)(ws + 2u * (1u << 20));
  __bf16* kdT = (__bf16*)(ws + 3u * (1u << 20));
  __bf16* vT = (__bf16*)(ws + 4u * (1u << 20));
  __bf16* kvsT = (__bf16*)(ws + 5u * (1u << 20));

  prep_kernel<<<384, 256, 0, stream>>>(x, xb, kvs, alpha, kvsT);
  gemm_fused_kernel<<<192, 512, 0, stream>>>(xb, W, alpha, qd, kd, kdT, vT);
  heads_kernel<<<256, 128, 0, stream>>>(qd, kd, kdT, vT, kvsT, kvs, alpha, out);
}